// Round 10
// baseline (245.802 us; speedup 1.0000x reference)
//
#include <hip/hip_runtime.h>
#include <hip/hip_bf16.h>

#define NPIX 4096

typedef __attribute__((ext_vector_type(16))) float f32x16;
typedef __attribute__((ext_vector_type(8))) short short8;

__device__ inline short f2bf(float f) {   // round-to-nearest-even
  unsigned u = __float_as_uint(f);
  u += 0x7FFF + ((u >> 16) & 1);
  return (short)(u >> 16);
}

__device__ inline void gload16(const short* g, short* l) {
  __builtin_amdgcn_global_load_lds(
      (const __attribute__((address_space(1))) void*)g,
      (__attribute__((address_space(3))) void*)l, 16, 0, 0);
}

// ---------------- projection (R5-proven 10-pass layout) + counter zeroing ----
// grid = 10 jobs x 64 blocks x 256 thr; thread = 1 pixel, 8 outputs.
// job 0: Q rows (xlog2e) -> Qp[B*N][8]; job 1: K -> Kp[B*N][8];
// jobs 2-9: V ch 8*(job-2)..+8 -> Vi[b][oct][e][ko] (oct=n>>3, ko=n&7)
__global__ __launch_bounds__(256) void proj_kernel(
    const float* __restrict__ x,
    const float* __restrict__ Wq, const float* __restrict__ bq,
    const float* __restrict__ Wk, const float* __restrict__ bk,
    const float* __restrict__ Wv, const float* __restrict__ bv,
    short* __restrict__ Qp, short* __restrict__ Kp, short* __restrict__ Vi,
    int* __restrict__ counters)
{
  if (blockIdx.x == 0 && threadIdx.x < 64) counters[threadIdx.x] = 0;  // for attn elect

  const int job = blockIdx.x >> 6;
  const int p = (blockIdx.x & 63) * 256 + threadIdx.x;
  const int b = p >> 12, n = p & 4095;
  const float* xb = x + ((size_t)b << 18) + n;

  float xv[64];
#pragma unroll
  for (int c = 0; c < 64; ++c) xv[c] = xb[(size_t)c << 12];

  if (job < 2) {
    const float* W    = job ? Wk : Wq;
    const float* bias = job ? bk : bq;
    float a[8];
#pragma unroll
    for (int d = 0; d < 8; ++d) {
      float acc = bias[d];
#pragma unroll
      for (int c = 0; c < 64; ++c) acc = fmaf(W[d * 64 + c], xv[c], acc);
      a[d] = acc;
    }
    short8 o;
    if (job == 0) {
#pragma unroll
      for (int d = 0; d < 8; ++d) o[d] = f2bf(a[d] * 1.44269504f);  // fold log2e
      *(short8*)(Qp + (size_t)p * 8) = o;
    } else {
#pragma unroll
      for (int d = 0; d < 8; ++d) o[d] = f2bf(a[d]);
      *(short8*)(Kp + (size_t)p * 8) = o;
    }
  } else {
    const int e0 = (job - 2) * 8;
    const size_t base = ((size_t)(b * 512 + (n >> 3)) * 64) * 8 + (n & 7);
#pragma unroll
    for (int i = 0; i < 8; ++i) {
      float acc = bv[e0 + i];
#pragma unroll
      for (int c = 0; c < 64; ++c) acc = fmaf(Wv[(e0 + i) * 64 + c], xv[c], acc);
      Vi[base + (size_t)(e0 + i) * 8] = f2bf(acc);
    }
  }
}

// T12 pack: 16 f32 weights -> two PV A-fragments (cvt_pk + permlane32_swap)
__device__ inline void pk_swap(const float* p, short8& A0, short8& A1) {
  unsigned u[8];
#pragma unroll
  for (int j = 0; j < 8; ++j)
    asm("v_cvt_pk_bf16_f32 %0, %1, %2" : "=v"(u[j]) : "v"(p[2 * j]), "v"(p[2 * j + 1]));
  asm("v_permlane32_swap_b32 %0, %1" : "+v"(u[0]), "+v"(u[2]));
  asm("v_permlane32_swap_b32 %0, %1" : "+v"(u[1]), "+v"(u[3]));
  asm("v_permlane32_swap_b32 %0, %1" : "+v"(u[4]), "+v"(u[6]));
  asm("v_permlane32_swap_b32 %0, %1" : "+v"(u[5]), "+v"(u[7]));
  union { unsigned w[4]; short8 s; } c0, c1;
  c0.w[0] = u[0]; c0.w[1] = u[1]; c0.w[2] = u[2]; c0.w[3] = u[3];
  c1.w[0] = u[4]; c1.w[1] = u[5]; c1.w[2] = u[6]; c1.w[3] = u[7];
  A0 = c0.s; A1 = c1.s;
}

// ---------------- fused attention + last-block combine ----------------
// grid 512 = (4 b) x (16 qg) x (8 ks); block = 8 waves (R9 structure).
// After writing its partial slot, each block fences + bumps counters[b*16+qg];
// the 8th (last) block combines all slots for its 256 q and writes out.
__global__ __launch_bounds__(512, 2) void attn_kernel(
    const short* __restrict__ Qp, const short* __restrict__ Kp,
    const short* __restrict__ Vi,
    short* __restrict__ accB, float* __restrict__ psumW,
    int* __restrict__ counters,
    const float* __restrict__ x, const float* __restrict__ gamma,
    float* __restrict__ out)
{
  __shared__ __align__(16) char smem[36872];
  short (*kLds)[1024] = (short (*)[1024])smem;             // [2][1024]  4 KB
  short (*vLds)[8192] = (short (*)[8192])(smem + 4096);    // [2][8192] 32 KB
  // combine-phase aliases (used only after staging is fully done):
  float (*accLds)[65] = (float (*)[65])smem;               // [128][65] 33280 B
  float* sInvL        = (float*)(smem + 33280);            // [256]      1 KB
  int*   lastF        = (int*)(smem + 34304);

  const int tid  = threadIdx.x;
  const int wv   = tid >> 6;
  const int lane = tid & 63;
  const int lo   = lane & 31;
  const int hi   = lane >> 5;

  const int bid = blockIdx.x;
  const int ks  = bid & 7;
  const int qg  = (bid >> 3) & 15;
  const int b   = bid >> 7;
  const int Qgbase = (b << 12) + qg * 256 + wv * 32;   // global q base of the wave
  const int slot = ks;

  short8 qf = {};
  if (hi == 0) qf = *(const short8*)(Qp + (size_t)(Qgbase + lo) * 8);

  const short* ksrc = Kp + ((size_t)(b << 12) + ks * 512) * 8;
  const short* vsrc = Vi + (size_t)b * 262144 + (size_t)ks * 32768;

  auto stage = [&](int c, int buf) {
    const short* vs = vsrc + (size_t)c * 8192;
    gload16(vs + (size_t)tid * 8,         &vLds[buf][(tid & ~63) * 8]);
    gload16(vs + (size_t)(tid + 512) * 8, &vLds[buf][((tid + 512) & ~63) * 8]);
    if (tid < 128)
      gload16(ksrc + (size_t)c * 1024 + (size_t)tid * 8, &kLds[buf][(tid & ~63) * 8]);
  };

  f32x16 acc0 = {}, acc1 = {};
  float psum = 0.f;
  const f32x16 z = {};

  stage(0, 0);
  __syncthreads();

  for (int c = 0; c < 4; ++c) {
    if (c < 3) stage(c + 1, (c + 1) & 1);
    const int buf = c & 1;
#pragma unroll
    for (int i = 0; i < 4; ++i) {
      short8 kf = *(const short8*)&kLds[buf][(i * 32 + lo) * 8];
      f32x16 en = __builtin_amdgcn_mfma_f32_32x32x16_bf16(kf, qf, z, 0, 0, 0);
      float p[16];
#pragma unroll
      for (int j = 0; j < 16; ++j) p[j] = __builtin_amdgcn_exp2f(en[j]);
#pragma unroll
      for (int j = 0; j < 16; ++j) psum += p[j];
      short8 a0, a1;
      pk_swap(p, a0, a1);
      short8 v00 = *(const short8*)&vLds[buf][(i * 4 + hi) * 512 + lo * 8];
      short8 v01 = *(const short8*)&vLds[buf][(i * 4 + hi) * 512 + (32 + lo) * 8];
      short8 v10 = *(const short8*)&vLds[buf][(i * 4 + 2 + hi) * 512 + lo * 8];
      short8 v11 = *(const short8*)&vLds[buf][(i * 4 + 2 + hi) * 512 + (32 + lo) * 8];
      __builtin_amdgcn_s_setprio(1);
      acc0 = __builtin_amdgcn_mfma_f32_32x32x16_bf16(a0, v00, acc0, 0, 0, 0);
      acc1 = __builtin_amdgcn_mfma_f32_32x32x16_bf16(a0, v01, acc1, 0, 0, 0);
      acc0 = __builtin_amdgcn_mfma_f32_32x32x16_bf16(a1, v10, acc0, 0, 0, 0);
      acc1 = __builtin_amdgcn_mfma_f32_32x32x16_bf16(a1, v11, acc1, 0, 0, 0);
      __builtin_amdgcn_s_setprio(0);
    }
    __syncthreads();   // drains staging vmcnt; readers done before overwrite
  }

  // ---- write partials ----
  float pfull = psum + __shfl_xor(psum, 32);
  if (hi == 0) psumW[slot * 16384 + Qgbase + lo] = pfull;
#pragma unroll
  for (int r = 0; r < 16; ++r) {
    const int q = (r & 3) + 8 * (r >> 2) + 4 * hi;   // D-layout row
    const size_t base = ((size_t)(slot * 16384 + Qgbase + q)) << 6;
    accB[base + lo]      = f2bf(acc0[r]);
    accB[base + 32 + lo] = f2bf(acc1[r]);
  }

  // ---- elect last block of this (b,qg) ----
  __threadfence();          // release: partials visible at device scope
  __syncthreads();          // all threads' stores+fence done
  if (tid == 0) {
    const int old = atomicAdd(&counters[b * 16 + qg], 1);
    *lastF = (old == 7);
  }
  __syncthreads();
  const bool last = (*lastF != 0);
  __syncthreads();          // lastF consumed before smem reuse
  if (!last) return;
  __threadfence();          // acquire side

  // ---- combine 8 slots for the 256 q of this (b,qg) ----
  const int Qbase = (b << 12) + qg * 256;
  const float g = gamma[0];
  if (tid < 256) {
    float s = 0.f;
#pragma unroll
    for (int sl = 0; sl < 8; ++sl) s += psumW[sl * 16384 + Qbase + tid];
    sInvL[tid] = g / s;
  }

#pragma unroll
  for (int pass = 0; pass < 2; ++pass) {
    const int q128 = pass * 128;
    __syncthreads();        // accLds free (prev pass readers / staging done)
    {
      const int e2 = tid & 31;         // e-pair
      const int qr = tid >> 5;         // 16 rows per sweep
#pragma unroll
      for (int sw = 0; sw < 8; ++sw) {
        const int qq = qr + sw * 16;
        const int gq = Qbase + q128 + qq;
        float s0 = 0.f, s1 = 0.f;
#pragma unroll
        for (int sl = 0; sl < 8; ++sl) {
          const unsigned u = *(const unsigned*)&accB[(((size_t)(sl * 16384 + gq)) << 6) + e2 * 2];
          s0 += __uint_as_float(u << 16);
          s1 += __uint_as_float(u & 0xFFFF0000u);
        }
        accLds[qq][e2 * 2]     = s0;
        accLds[qq][e2 * 2 + 1] = s1;
      }
    }
    __syncthreads();
    {
      const int q  = tid & 127;
      const int er = tid >> 7;         // 0..3
      const int n  = qg * 256 + q128 + q;
      const float si = sInvL[q128 + q];
#pragma unroll
      for (int k = 0; k < 16; ++k) {
        const int e = er + k * 4;
        const size_t idx = ((size_t)(b * 64 + e) << 12) + n;
        out[idx] = fmaf(si, accLds[q][e], x[idx]);
      }
    }
  }
}

extern "C" void kernel_launch(void* const* d_in, const int* in_sizes, int n_in,
                              void* d_out, int out_size, void* d_ws, size_t ws_size,
                              hipStream_t stream) {
  const float* x     = (const float*)d_in[0];
  const float* Wq    = (const float*)d_in[1];
  const float* bq    = (const float*)d_in[2];
  const float* Wk    = (const float*)d_in[3];
  const float* bk    = (const float*)d_in[4];
  const float* Wv    = (const float*)d_in[5];
  const float* bv    = (const float*)d_in[6];
  const float* gamma = (const float*)d_in[7];
  float* out = (float*)d_out;

  short* ws     = (short*)d_ws;
  short* Qp     = ws;                        // 131072 shorts
  short* Kp     = ws + 131072;               // 131072 shorts
  short* Vi     = ws + 262144;               // 1048576 shorts: [4][512][64][8]
  short* accB   = ws + 1310720;              // 8*16384*64 shorts = 16 MB
  float* psumW  = (float*)(ws + 9699328);    // 8*16384 floats = 512 KB
  int* counters = (int*)(ws + 9961472);      // 64 ints

  proj_kernel<<<640, 256, 0, stream>>>(x, Wq, bq, Wk, bk, Wv, bv, Qp, Kp, Vi, counters);
  attn_kernel<<<512, 512, 0, stream>>>(Qp, Kp, Vi, accB, psumW, counters, x, gamma, out);
}